// Round 18
// baseline (262.514 us; speedup 1.0000x reference)
//
#include <hip/hip_runtime.h>

#define NA 5
#define LL 500
#define DD 300
#define H1 10
#define H2 50
#define NB 256
#define ADS 11   // adoc LDS row stride (odd -> conflict-free column access)

// One block per (side, batch): grid = 512, 512 threads. ROUND-18 CHANGE vs
// r17: channel-split pair placed in ADJACENT LANES of the same wave
// (cs = tid&1, t = tid>>1) so both cs-threads of a token issue the SAME
// gather address in the SAME load instruction -> coalescer merges to one
// transaction; gather traffic is 1x by construction. (r17 put the pair in
// different waves -> timing skew -> L1/L2 misses -> FETCH 1.7x, regress.)
// Inner loop (w[40] b128), AP 2-pass staging, phase 2: r16/r17 verbatim.

__global__ __launch_bounds__(512, 1)
void k_aspect(const int* __restrict__ Uids, const int* __restrict__ Iids,
              const int* __restrict__ Udocs, const int* __restrict__ Idocs,
              const float* __restrict__ Wemb,
              const float* __restrict__ AE,   // [A][30]
              const float* __restrict__ AP,   // [A][D][H1]
              float* __restrict__ Rep)        // [2][B][A][H1]
{
    extern __shared__ char smem[];
    float* apS = (float*)smem;                                  // 7600 f = 30400 B
    float (*adoc)[ADS] = (float(*)[ADS])(smem + 30400);         // 22000 B
    float* lg = (float*)(smem + 30400 + 22000);                 // 2000 B

    const int tid  = threadIdx.x;
    const int bid  = blockIdx.x;
    const int side = bid >> 8;
    const int b    = bid & 255;

    const int cs = tid & 1;            // channel group (adjacent lanes!)
    const int t  = tid >> 1;           // token slot 0..255
    const bool act = (t < 250);

    const int* ids  = side ? Iids : Uids;
    const int* docs = side ? Idocs : Udocs;

    const int uid = ids[b];
    const int* doc = docs + (long)uid * LL;

    // ---- phase 1: 2 tokens/thread, 25 channels each ----
    float accA[25], accB[25];
    #pragma unroll
    for (int c = 0; c < 25; ++c) { accA[c] = 0.f; accB[c] = 0.f; }

    const float4* e4A = nullptr;
    const float4* e4B = nullptr;
    float4 a0, a1, b0, b1;
    a0 = a1 = b0 = b1 = make_float4(0.f, 0.f, 0.f, 0.f);
    if (act) {
        const int tokA = doc[t];           // lanes 2i/2i+1: same addr -> merged
        const int tokB = doc[t + 250];
        e4A = (const float4*)(Wemb + (long)tokA * DD);
        e4B = (const float4*)(Wemb + (long)tokB * DD);
        a0 = e4A[0]; a1 = e4A[1];
        b0 = e4B[0]; b1 = e4B[1];
    }

    const int db0s[3] = {0, 38, 75};
    #pragma unroll
    for (int p = 0; p < 2; ++p) {
        const int db0 = db0s[p], db1 = db0s[p + 1];
        const int nf4 = (db1 - db0) * 10;          // float4 per aspect (380 or 370)

        __syncthreads();                            // previous slice fully consumed
        for (int i = tid; i < NA * 380; i += 512) { // stage slice
            const int a_ = i / 380, j = i - a_ * 380;
            if (j < nf4) {
                ((float4*)(apS + a_ * 1520))[j] =
                    ((const float4*)(AP + a_ * (DD * H1) + db0 * 40))[j];
            }
        }
        __syncthreads();

        if (act) {
            for (int db = db0; db < db1; ++db) {
                float4 a2 = a1, b2 = b1;
                if (db < 73) { a2 = e4A[db + 2]; b2 = e4B[db + 2]; }  // 2-deep prefetch
                const float av0 = a0.x, av1 = a0.y, av2 = a0.z, av3 = a0.w;
                const float bv0 = b0.x, bv1 = b0.y, bv2 = b0.z, bv3 = b0.w;
                const int o = (db - db0) * 40;
                if (cs == 0) {
                    #pragma unroll
                    for (int a_ = 0; a_ < 3; ++a_) {
                        const float4* wp4 = (const float4*)(apS + a_ * 1520 + o);
                        float w[40];
                        #pragma unroll
                        for (int j = 0; j < 10; ++j)
                            *reinterpret_cast<float4*>(&w[4 * j]) = wp4[j];
                        const int hn = (a_ == 2) ? 5 : H1;
                        #pragma unroll
                        for (int h = 0; h < H1; ++h) {
                            if (h < hn) {
                                const float w0 = w[h], w1 = w[10 + h],
                                            w2 = w[20 + h], w3 = w[30 + h];
                                accA[a_ * H1 + h] += av0 * w0 + av1 * w1 + av2 * w2 + av3 * w3;
                                accB[a_ * H1 + h] += bv0 * w0 + bv1 * w1 + bv2 * w2 + bv3 * w3;
                            }
                        }
                    }
                } else {
                    #pragma unroll
                    for (int a_ = 2; a_ < 5; ++a_) {
                        const float4* wp4 = (const float4*)(apS + a_ * 1520 + o);
                        float w[40];
                        #pragma unroll
                        for (int j = 0; j < 10; ++j)
                            *reinterpret_cast<float4*>(&w[4 * j]) = wp4[j];
                        const int h0 = (a_ == 2) ? 5 : 0;
                        #pragma unroll
                        for (int h = 0; h < H1; ++h) {
                            if (h >= h0) {
                                const float w0 = w[h], w1 = w[10 + h],
                                            w2 = w[20 + h], w3 = w[30 + h];
                                accA[a_ * H1 + h - 25] += av0 * w0 + av1 * w1 + av2 * w2 + av3 * w3;
                                accB[a_ * H1 + h - 25] += bv0 * w0 + bv1 * w1 + bv2 * w2 + bv3 * w3;
                            }
                        }
                    }
                }
                a0 = a1; a1 = a2;
                b0 = b1; b1 = b2;
            }
        }
    }

    // ---- phase 2: one aspect at a time through LDS (chains verbatim) ----
    #pragma unroll
    for (int a_ = 0; a_ < NA; ++a_) {
        __syncthreads();
        if (act) {
            #pragma unroll
            for (int h = 0; h < H1; ++h) {
                const int c = a_ * H1 + h;
                if (cs == 0 && c < 25) {
                    adoc[t][h]       = accA[c];
                    adoc[t + 250][h] = accB[c];
                }
                if (cs == 1 && c >= 25) {
                    adoc[t][h]       = accA[c - 25];
                    adoc[t + 250][h] = accB[c - 25];
                }
            }
        }
        __syncthreads();

        // window logits (exact chain; thread tid handles l = tid)
        if (tid < LL) {
            const float* aerow = AE + a_ * 30;      // uniform -> s_load (600 B, hot)
            float s = 0.f;
            if (tid > 0) {
                const float* ad = &adoc[tid - 1][0];
                #pragma unroll
                for (int h = 0; h < H1; ++h) s += ad[h] * aerow[h];
            }
            {
                const float* ad = &adoc[tid][0];
                #pragma unroll
                for (int h = 0; h < H1; ++h) s += ad[h] * aerow[H1 + h];
            }
            if (tid < LL - 1) {
                const float* ad = &adoc[tid + 1][0];
                #pragma unroll
                for (int h = 0; h < H1; ++h) s += ad[h] * aerow[2 * H1 + h];
            }
            lg[tid] = s;
        }
        __syncthreads();

        // softmax over L + weighted sum (wave 0; exact reduction)
        if (tid < 64) {
            const int lane = tid;
            float mx = -1e30f;
            for (int p = lane; p < LL; p += 64) mx = fmaxf(mx, lg[p]);
            #pragma unroll
            for (int o = 32; o; o >>= 1) mx = fmaxf(mx, __shfl_xor(mx, o, 64));
            float sum = 0.f;
            for (int p = lane; p < LL; p += 64) {
                float pr = expf(lg[p] - mx);
                lg[p] = pr;
                sum += pr;
            }
            #pragma unroll
            for (int o = 32; o; o >>= 1) sum += __shfl_xor(sum, o, 64);
            float r[H1];
            #pragma unroll
            for (int h = 0; h < H1; ++h) r[h] = 0.f;
            for (int p = lane; p < LL; p += 64) {
                const float pr = lg[p];
                const float* ad = &adoc[p][0];
                #pragma unroll
                for (int h = 0; h < H1; ++h) r[h] += pr * ad[h];
            }
            #pragma unroll
            for (int h = 0; h < H1; ++h) {
                #pragma unroll
                for (int o = 32; o; o >>= 1) r[h] += __shfl_xor(r[h], o, 64);
            }
            if (lane == 0) {
                const float inv = 1.f / sum;
                float* out = Rep + (((long)side * NB + b) * NA + a_) * H1;
                #pragma unroll
                for (int h = 0; h < H1; ++h) out[h] = r[h] * inv;
            }
        }
    }
}

__global__ __launch_bounds__(64)
void k_final(const float* __restrict__ Rep, const int* __restrict__ Uids,
             const int* __restrict__ Iids, const float* __restrict__ M,
             const float* __restrict__ Uproj, const float* __restrict__ Uw,
             const float* __restrict__ Iproj, const float* __restrict__ Iw,
             const float* __restrict__ Bu, const float* __restrict__ Bi,
             const float* __restrict__ Bg, float* __restrict__ out)
{
    __shared__ float Ud[50], Idd[50], tmp[50], aff[25];
    const int b = blockIdx.x, lane = threadIdx.x;
    if (lane < 50) {
        Ud[lane]  = Rep[(long)b * 50 + lane];
        Idd[lane] = Rep[(long)NB * 50 + (long)b * 50 + lane];
    }
    __syncthreads();
    if (lane < 50) {  // tmp[c][h] = sum_k M[h][k] * Id[c][k]
        const int c = lane / 10, h = lane % 10;
        float t = 0.f;
        #pragma unroll
        for (int k = 0; k < 10; ++k) t += M[h * 10 + k] * Idd[c * 10 + k];
        tmp[lane] = t;
    }
    __syncthreads();
    if (lane < 25) {  // aff[a][c] = relu(sum_h Ud[a][h] * tmp[c][h])
        const int a_ = lane / 5, c = lane % 5;
        float s = 0.f;
        #pragma unroll
        for (int h = 0; h < 10; ++h) s += Ud[a_ * 10 + h] * tmp[c * 10 + h];
        aff[lane] = fmaxf(s, 0.f);
    }
    __syncthreads();

    float hu1[5], hi1[5], tu[5], ti[5];
    if (lane < 50) {
        #pragma unroll
        for (int a_ = 0; a_ < 5; ++a_) {
            float su = 0.f, si = 0.f;
            #pragma unroll
            for (int h = 0; h < 10; ++h) {
                su += Uproj[lane * 10 + h] * Ud[a_ * 10 + h];
                si += Iproj[lane * 10 + h] * Idd[a_ * 10 + h];
            }
            hu1[a_] = su; hi1[a_] = si;
        }
    } else {
        #pragma unroll
        for (int a_ = 0; a_ < 5; ++a_) { hu1[a_] = 0.f; hi1[a_] = 0.f; }
    }
    const float uw = (lane < 50) ? Uw[lane] : 0.f;
    const float iw = (lane < 50) ? Iw[lane] : 0.f;
    #pragma unroll
    for (int a_ = 0; a_ < 5; ++a_) {
        float hu = hu1[a_], hi = hi1[a_];
        #pragma unroll
        for (int c = 0; c < 5; ++c) {
            hu += hi1[c] * aff[a_ * 5 + c];   // Hu[e][a] += Hi1[e][c]*aff[a][c]
            hi += hu1[c] * aff[c * 5 + a_];   // Hi[e][c] += Hu1[e][a]*aff[a][c]
        }
        tu[a_] = uw * fmaxf(hu, 0.f);
        ti[a_] = iw * fmaxf(hi, 0.f);
    }
    #pragma unroll
    for (int a_ = 0; a_ < 5; ++a_) {
        #pragma unroll
        for (int o = 32; o; o >>= 1) {
            tu[a_] += __shfl_xor(tu[a_], o, 64);
            ti[a_] += __shfl_xor(ti[a_], o, 64);
        }
    }
    if (lane == 0) {
        float mu = tu[0], mi = ti[0];
        #pragma unroll
        for (int a_ = 1; a_ < 5; ++a_) { mu = fmaxf(mu, tu[a_]); mi = fmaxf(mi, ti[a_]); }
        float eu[5], ei[5], su = 0.f, si = 0.f;
        #pragma unroll
        for (int a_ = 0; a_ < 5; ++a_) {
            eu[a_] = expf(tu[a_] - mu); su += eu[a_];
            ei[a_] = expf(ti[a_] - mi); si += ei[a_];
        }
        float R = 0.f;
        #pragma unroll
        for (int a_ = 0; a_ < 5; ++a_) {
            float ar = 0.f;
            #pragma unroll
            for (int h = 0; h < 10; ++h) ar += Ud[a_ * 10 + h] * Idd[a_ * 10 + h];
            R += (eu[a_] / su) * (ei[a_] / si) * ar;
        }
        R += Bu[Uids[b]] + Bi[Iids[b]] + Bg[0];
        out[b] = R;
    }
}

extern "C" void kernel_launch(void* const* d_in, const int* in_sizes, int n_in,
                              void* d_out, int out_size, void* d_ws, size_t ws_size,
                              hipStream_t stream)
{
    const int*   Uids  = (const int*)d_in[0];
    const int*   Iids  = (const int*)d_in[1];
    const int*   Udocs = (const int*)d_in[2];
    const int*   Idocs = (const int*)d_in[3];
    const float* Wemb  = (const float*)d_in[4];
    const float* AE    = (const float*)d_in[5];
    const float* AP    = (const float*)d_in[6];
    const float* M     = (const float*)d_in[7];
    const float* Uproj = (const float*)d_in[8];
    const float* Uw    = (const float*)d_in[9];
    const float* Iproj = (const float*)d_in[10];
    const float* Iw    = (const float*)d_in[11];
    const float* Bu    = (const float*)d_in[12];
    const float* Bi    = (const float*)d_in[13];
    const float* Bg    = (const float*)d_in[14];

    float* Rep = (float*)d_ws;        // [2][256][5][10] = 102400 B
    float* out = (float*)d_out;

    const size_t smem = 30400 + 22000 + 2000;   // apS + adoc + lg = 54400 B
    k_aspect<<<2 * NB, 512, smem, stream>>>(Uids, Iids, Udocs, Idocs, Wemb, AE, AP, Rep);
    k_final<<<NB, 64, 0, stream>>>(Rep, Uids, Iids, M, Uproj, Uw, Iproj, Iw, Bu, Bi, Bg, out);
}

// Round 19
// 171.685 us; speedup vs baseline: 1.5290x; 1.5290x over previous
//
#include <hip/hip_runtime.h>

#define NA 5
#define LL 500
#define DD 300
#define H1 10
#define H2 50
#define NB 256
#define ADS 11   // adoc LDS row stride (odd -> conflict-free column access)

// One block per (side, batch): grid = 512, 512 threads. r19 = r18's
// adjacent-lane token pairing (cs = tid&1 -> coalescer merges the pair's
// identical gather addresses; FETCH 1x proven in r18) + DIVERGENCE-FREE
// channel split: cs selects h-half (h = cs*5..cs*5+4) for ALL aspects —
// cs appears only in address arithmetic, never in a branch (r18's
// aspect-split branch ran both bodies half-masked: VALU 67% but 2x insts).
// Staging remaps each 40-float (a,db) slice into two contiguous 20-float
// halves so each cs-group reads its half as 5 x ds_read_b128. Per-channel
// d-order and FMA expressions identical to r9-r18 (absmax 0.0 lineage).

__global__ __launch_bounds__(512, 1)
void k_aspect(const int* __restrict__ Uids, const int* __restrict__ Iids,
              const int* __restrict__ Udocs, const int* __restrict__ Idocs,
              const float* __restrict__ Wemb,
              const float* __restrict__ AE,   // [A][30]
              const float* __restrict__ AP,   // [A][D][H1]
              float* __restrict__ Rep)        // [2][B][A][H1]
{
    extern __shared__ char smem[];
    float* apS = (float*)smem;                                  // 7600 f = 30400 B
    float (*adoc)[ADS] = (float(*)[ADS])(smem + 30400);         // 22000 B
    float* lg = (float*)(smem + 30400 + 22000);                 // 2000 B

    const int tid  = threadIdx.x;
    const int bid  = blockIdx.x;
    const int side = bid >> 8;
    const int b    = bid & 255;

    const int cs = tid & 1;            // h-half (address-only, no branch)
    const int t  = tid >> 1;           // token slot 0..255
    const bool act = (t < 250);

    const int* ids  = side ? Iids : Uids;
    const int* docs = side ? Idocs : Udocs;

    const int uid = ids[b];
    const int* doc = docs + (long)uid * LL;

    // ---- phase 1: 2 tokens/thread, 25 channels (5 aspects x 5 h) ----
    float accA[25], accB[25];
    #pragma unroll
    for (int c = 0; c < 25; ++c) { accA[c] = 0.f; accB[c] = 0.f; }

    const float4* e4A = nullptr;
    const float4* e4B = nullptr;
    float4 a0, a1, b0, b1;
    a0 = a1 = b0 = b1 = make_float4(0.f, 0.f, 0.f, 0.f);
    if (act) {
        const int tokA = doc[t];           // lanes 2i/2i+1: same addr -> merged
        const int tokB = doc[t + 250];
        e4A = (const float4*)(Wemb + (long)tokA * DD);
        e4B = (const float4*)(Wemb + (long)tokB * DD);
        a0 = e4A[0]; a1 = e4A[1];
        b0 = e4B[0]; b1 = e4B[1];
    }

    const int db0s[3] = {0, 38, 75};
    #pragma unroll
    for (int p = 0; p < 2; ++p) {
        const int db0 = db0s[p], db1 = db0s[p + 1];
        const int nf4 = (db1 - db0) * 10;          // float4 per aspect slice

        __syncthreads();                            // previous slice fully consumed
        // stage with remap: slice float q = db_rel*40 + dd*10 + h  ->
        //   apS[a*1520 + db_rel*40 + (h/5)*20 + dd*5 + h%5]
        for (int i = tid; i < NA * 380; i += 512) {
            const int a_ = i / 380, j = i - a_ * 380;
            if (j < nf4) {
                const float4 v = ((const float4*)(AP + a_ * (DD * H1) + db0 * 40))[j];
                #pragma unroll
                for (int k = 0; k < 4; ++k) {
                    const int q  = 4 * j + k;
                    const int dr = q / 40;
                    const int r  = q - dr * 40;
                    const int dd = r / 10, h = r - dd * 10;
                    const int cg = h / 5,  hp = h - cg * 5;
                    apS[a_ * 1520 + dr * 40 + cg * 20 + dd * 5 + hp] =
                        ((const float*)&v)[k];
                }
            }
        }
        __syncthreads();

        if (act) {
            for (int db = db0; db < db1; ++db) {
                float4 a2 = a1, b2 = b1;
                if (db < 73) { a2 = e4A[db + 2]; b2 = e4B[db + 2]; }  // 2-deep prefetch
                const float av0 = a0.x, av1 = a0.y, av2 = a0.z, av3 = a0.w;
                const float bv0 = b0.x, bv1 = b0.y, bv2 = b0.z, bv3 = b0.w;
                const int o = (db - db0) * 40 + cs * 20;   // 16B-aligned
                #pragma unroll
                for (int a_ = 0; a_ < NA; ++a_) {
                    const float4* wp4 = (const float4*)(apS + a_ * 1520 + o);
                    float w[20];
                    #pragma unroll
                    for (int j = 0; j < 5; ++j)
                        *reinterpret_cast<float4*>(&w[4 * j]) = wp4[j];
                    #pragma unroll
                    for (int hp = 0; hp < 5; ++hp) {
                        const float w0 = w[hp],      w1 = w[5 + hp],
                                    w2 = w[10 + hp], w3 = w[15 + hp];
                        accA[a_ * 5 + hp] += av0 * w0 + av1 * w1 + av2 * w2 + av3 * w3;
                        accB[a_ * 5 + hp] += bv0 * w0 + bv1 * w1 + bv2 * w2 + bv3 * w3;
                    }
                }
                a0 = a1; a1 = a2;
                b0 = b1; b1 = b2;
            }
        }
    }

    // ---- phase 2: one aspect at a time through LDS (chains verbatim) ----
    #pragma unroll
    for (int a_ = 0; a_ < NA; ++a_) {
        __syncthreads();
        if (act) {
            #pragma unroll
            for (int hp = 0; hp < 5; ++hp) {
                adoc[t][cs * 5 + hp]       = accA[a_ * 5 + hp];
                adoc[t + 250][cs * 5 + hp] = accB[a_ * 5 + hp];
            }
        }
        __syncthreads();

        // window logits (exact chain; thread tid handles l = tid)
        if (tid < LL) {
            const float* aerow = AE + a_ * 30;      // uniform -> s_load (600 B, hot)
            float s = 0.f;
            if (tid > 0) {
                const float* ad = &adoc[tid - 1][0];
                #pragma unroll
                for (int h = 0; h < H1; ++h) s += ad[h] * aerow[h];
            }
            {
                const float* ad = &adoc[tid][0];
                #pragma unroll
                for (int h = 0; h < H1; ++h) s += ad[h] * aerow[H1 + h];
            }
            if (tid < LL - 1) {
                const float* ad = &adoc[tid + 1][0];
                #pragma unroll
                for (int h = 0; h < H1; ++h) s += ad[h] * aerow[2 * H1 + h];
            }
            lg[tid] = s;
        }
        __syncthreads();

        // softmax over L + weighted sum (wave 0; exact reduction)
        if (tid < 64) {
            const int lane = tid;
            float mx = -1e30f;
            for (int p = lane; p < LL; p += 64) mx = fmaxf(mx, lg[p]);
            #pragma unroll
            for (int o = 32; o; o >>= 1) mx = fmaxf(mx, __shfl_xor(mx, o, 64));
            float sum = 0.f;
            for (int p = lane; p < LL; p += 64) {
                float pr = expf(lg[p] - mx);
                lg[p] = pr;
                sum += pr;
            }
            #pragma unroll
            for (int o = 32; o; o >>= 1) sum += __shfl_xor(sum, o, 64);
            float r[H1];
            #pragma unroll
            for (int h = 0; h < H1; ++h) r[h] = 0.f;
            for (int p = lane; p < LL; p += 64) {
                const float pr = lg[p];
                const float* ad = &adoc[p][0];
                #pragma unroll
                for (int h = 0; h < H1; ++h) r[h] += pr * ad[h];
            }
            #pragma unroll
            for (int h = 0; h < H1; ++h) {
                #pragma unroll
                for (int o = 32; o; o >>= 1) r[h] += __shfl_xor(r[h], o, 64);
            }
            if (lane == 0) {
                const float inv = 1.f / sum;
                float* out = Rep + (((long)side * NB + b) * NA + a_) * H1;
                #pragma unroll
                for (int h = 0; h < H1; ++h) out[h] = r[h] * inv;
            }
        }
    }
}

__global__ __launch_bounds__(64)
void k_final(const float* __restrict__ Rep, const int* __restrict__ Uids,
             const int* __restrict__ Iids, const float* __restrict__ M,
             const float* __restrict__ Uproj, const float* __restrict__ Uw,
             const float* __restrict__ Iproj, const float* __restrict__ Iw,
             const float* __restrict__ Bu, const float* __restrict__ Bi,
             const float* __restrict__ Bg, float* __restrict__ out)
{
    __shared__ float Ud[50], Idd[50], tmp[50], aff[25];
    const int b = blockIdx.x, lane = threadIdx.x;
    if (lane < 50) {
        Ud[lane]  = Rep[(long)b * 50 + lane];
        Idd[lane] = Rep[(long)NB * 50 + (long)b * 50 + lane];
    }
    __syncthreads();
    if (lane < 50) {  // tmp[c][h] = sum_k M[h][k] * Id[c][k]
        const int c = lane / 10, h = lane % 10;
        float t = 0.f;
        #pragma unroll
        for (int k = 0; k < 10; ++k) t += M[h * 10 + k] * Idd[c * 10 + k];
        tmp[lane] = t;
    }
    __syncthreads();
    if (lane < 25) {  // aff[a][c] = relu(sum_h Ud[a][h] * tmp[c][h])
        const int a_ = lane / 5, c = lane % 5;
        float s = 0.f;
        #pragma unroll
        for (int h = 0; h < 10; ++h) s += Ud[a_ * 10 + h] * tmp[c * 10 + h];
        aff[lane] = fmaxf(s, 0.f);
    }
    __syncthreads();

    float hu1[5], hi1[5], tu[5], ti[5];
    if (lane < 50) {
        #pragma unroll
        for (int a_ = 0; a_ < 5; ++a_) {
            float su = 0.f, si = 0.f;
            #pragma unroll
            for (int h = 0; h < 10; ++h) {
                su += Uproj[lane * 10 + h] * Ud[a_ * 10 + h];
                si += Iproj[lane * 10 + h] * Idd[a_ * 10 + h];
            }
            hu1[a_] = su; hi1[a_] = si;
        }
    } else {
        #pragma unroll
        for (int a_ = 0; a_ < 5; ++a_) { hu1[a_] = 0.f; hi1[a_] = 0.f; }
    }
    const float uw = (lane < 50) ? Uw[lane] : 0.f;
    const float iw = (lane < 50) ? Iw[lane] : 0.f;
    #pragma unroll
    for (int a_ = 0; a_ < 5; ++a_) {
        float hu = hu1[a_], hi = hi1[a_];
        #pragma unroll
        for (int c = 0; c < 5; ++c) {
            hu += hi1[c] * aff[a_ * 5 + c];   // Hu[e][a] += Hi1[e][c]*aff[a][c]
            hi += hu1[c] * aff[c * 5 + a_];   // Hi[e][c] += Hu1[e][a]*aff[a][c]
        }
        tu[a_] = uw * fmaxf(hu, 0.f);
        ti[a_] = iw * fmaxf(hi, 0.f);
    }
    #pragma unroll
    for (int a_ = 0; a_ < 5; ++a_) {
        #pragma unroll
        for (int o = 32; o; o >>= 1) {
            tu[a_] += __shfl_xor(tu[a_], o, 64);
            ti[a_] += __shfl_xor(ti[a_], o, 64);
        }
    }
    if (lane == 0) {
        float mu = tu[0], mi = ti[0];
        #pragma unroll
        for (int a_ = 1; a_ < 5; ++a_) { mu = fmaxf(mu, tu[a_]); mi = fmaxf(mi, ti[a_]); }
        float eu[5], ei[5], su = 0.f, si = 0.f;
        #pragma unroll
        for (int a_ = 0; a_ < 5; ++a_) {
            eu[a_] = expf(tu[a_] - mu); su += eu[a_];
            ei[a_] = expf(ti[a_] - mi); si += ei[a_];
        }
        float R = 0.f;
        #pragma unroll
        for (int a_ = 0; a_ < 5; ++a_) {
            float ar = 0.f;
            #pragma unroll
            for (int h = 0; h < 10; ++h) ar += Ud[a_ * 10 + h] * Idd[a_ * 10 + h];
            R += (eu[a_] / su) * (ei[a_] / si) * ar;
        }
        R += Bu[Uids[b]] + Bi[Iids[b]] + Bg[0];
        out[b] = R;
    }
}

extern "C" void kernel_launch(void* const* d_in, const int* in_sizes, int n_in,
                              void* d_out, int out_size, void* d_ws, size_t ws_size,
                              hipStream_t stream)
{
    const int*   Uids  = (const int*)d_in[0];
    const int*   Iids  = (const int*)d_in[1];
    const int*   Udocs = (const int*)d_in[2];
    const int*   Idocs = (const int*)d_in[3];
    const float* Wemb  = (const float*)d_in[4];
    const float* AE    = (const float*)d_in[5];
    const float* AP    = (const float*)d_in[6];
    const float* M     = (const float*)d_in[7];
    const float* Uproj = (const float*)d_in[8];
    const float* Uw    = (const float*)d_in[9];
    const float* Iproj = (const float*)d_in[10];
    const float* Iw    = (const float*)d_in[11];
    const float* Bu    = (const float*)d_in[12];
    const float* Bi    = (const float*)d_in[13];
    const float* Bg    = (const float*)d_in[14];

    float* Rep = (float*)d_ws;        // [2][256][5][10] = 102400 B
    float* out = (float*)d_out;

    const size_t smem = 30400 + 22000 + 2000;   // apS + adoc + lg = 54400 B
    k_aspect<<<2 * NB, 512, smem, stream>>>(Uids, Iids, Udocs, Idocs, Wemb, AE, AP, Rep);
    k_final<<<NB, 64, 0, stream>>>(Rep, Uids, Iids, M, Uproj, Uw, Iproj, Iw, Bu, Bi, Bg, out);
}

// Round 20
// 158.586 us; speedup vs baseline: 1.6553x; 1.0826x over previous
//
#include <hip/hip_runtime.h>

#define NA 5
#define LL 500
#define DD 300
#define H1 10
#define H2 50
#define NB 256
#define ADS 11   // adoc LDS row stride (odd -> conflict-free column access)

// One block per (side, batch): grid = 512, 256 threads, 2 tokens/thread,
// all 50 channels per thread (r16 inner loop VERBATIM: wave-uniform
// ds_read_b128 broadcast of w[40], zero conflicts, absmax-0.0 chains).
// ROUND-20 CHANGE: AP staged in 4 K-passes (slice 15.2 KB, r14's proven
// staging) -> LDS 39.2 KB -> 4 blocks/CU = 4 waves/SIMD (2x r16) to cover
// the ds_read->FMA dependency stalls that pinned r16's VALU at 49%.
// VGPR 88 -> 4 waves/SIMD allowed (cap at 128). Gather untouched.

__global__ __launch_bounds__(256, 1)
void k_aspect(const int* __restrict__ Uids, const int* __restrict__ Iids,
              const int* __restrict__ Udocs, const int* __restrict__ Idocs,
              const float* __restrict__ Wemb,
              const float* __restrict__ AE,   // [A][30]
              const float* __restrict__ AP,   // [A][D][H1]
              float* __restrict__ Rep)        // [2][B][A][H1]
{
    extern __shared__ char smem[];
    float* apS = (float*)smem;                                  // 3800 f = 15200 B
    float (*adoc)[ADS] = (float(*)[ADS])(smem + 15200);         // 22000 B
    float* lg = (float*)(smem + 15200 + 22000);                 // 2000 B

    const int tid  = threadIdx.x;
    const int bid  = blockIdx.x;
    const int side = bid >> 8;
    const int b    = bid & 255;

    const int* ids  = side ? Iids : Uids;
    const int* docs = side ? Idocs : Udocs;

    const int uid = ids[b];
    const int* doc = docs + (long)uid * LL;

    // ---- phase 1: 2 tokens/thread, 50 channels each, registers only ----
    float accA[NA * H1], accB[NA * H1];
    #pragma unroll
    for (int c = 0; c < NA * H1; ++c) { accA[c] = 0.f; accB[c] = 0.f; }

    const bool act = (tid < 250);
    const float4* e4A = nullptr;
    const float4* e4B = nullptr;
    float4 a0, a1, b0, b1;
    a0 = a1 = b0 = b1 = make_float4(0.f, 0.f, 0.f, 0.f);
    if (act) {
        const int tokA = doc[tid];
        const int tokB = doc[tid + 250];
        e4A = (const float4*)(Wemb + (long)tokA * DD);
        e4B = (const float4*)(Wemb + (long)tokB * DD);
        a0 = e4A[0]; a1 = e4A[1];
        b0 = e4B[0]; b1 = e4B[1];
    }

    const int db0s[5] = {0, 19, 38, 57, 75};
    #pragma unroll
    for (int p = 0; p < 4; ++p) {
        const int db0 = db0s[p], db1 = db0s[p + 1];
        const int nf4 = (db1 - db0) * 10;          // float4 per aspect (190 or 180)

        __syncthreads();                            // previous slice fully consumed
        for (int i = tid; i < NA * 190; i += 256) { // stage slice
            const int a_ = i / 190, j = i - a_ * 190;
            if (j < nf4) {
                ((float4*)(apS + a_ * 760))[j] =
                    ((const float4*)(AP + a_ * (DD * H1) + db0 * 40))[j];
            }
        }
        __syncthreads();

        if (act) {
            for (int db = db0; db < db1; ++db) {
                float4 a2 = a1, b2 = b1;
                if (db < 73) { a2 = e4A[db + 2]; b2 = e4B[db + 2]; }  // 2-deep prefetch
                const float av0 = a0.x, av1 = a0.y, av2 = a0.z, av3 = a0.w;
                const float bv0 = b0.x, bv1 = b0.y, bv2 = b0.z, bv3 = b0.w;
                const int o = (db - db0) * 40;
                #pragma unroll
                for (int a_ = 0; a_ < NA; ++a_) {
                    // bulk b128 broadcast load of the 40-float slice -> registers
                    const float4* wp4 = (const float4*)(apS + a_ * 760 + o);
                    float w[40];
                    #pragma unroll
                    for (int j = 0; j < 10; ++j)
                        *reinterpret_cast<float4*>(&w[4 * j]) = wp4[j];
                    #pragma unroll
                    for (int h = 0; h < H1; ++h) {
                        const float w0 = w[h], w1 = w[10 + h],
                                    w2 = w[20 + h], w3 = w[30 + h];
                        accA[a_ * H1 + h] += av0 * w0 + av1 * w1 + av2 * w2 + av3 * w3;
                        accB[a_ * H1 + h] += bv0 * w0 + bv1 * w1 + bv2 * w2 + bv3 * w3;
                    }
                }
                a0 = a1; a1 = a2;
                b0 = b1; b1 = b2;
            }
        }
    }

    // ---- phase 2: one aspect at a time through LDS (chains verbatim) ----
    #pragma unroll
    for (int a_ = 0; a_ < NA; ++a_) {
        __syncthreads();
        if (act) {
            #pragma unroll
            for (int h = 0; h < H1; ++h) {
                adoc[tid][h]       = accA[a_ * H1 + h];
                adoc[tid + 250][h] = accB[a_ * H1 + h];
            }
        }
        __syncthreads();

        // window logits (exact chain, strided by 256)
        for (int l = tid; l < LL; l += 256) {
            const float* aerow = AE + a_ * 30;      // uniform -> s_load (600 B, hot)
            float s = 0.f;
            if (l > 0) {
                const float* ad = &adoc[l - 1][0];
                #pragma unroll
                for (int h = 0; h < H1; ++h) s += ad[h] * aerow[h];
            }
            {
                const float* ad = &adoc[l][0];
                #pragma unroll
                for (int h = 0; h < H1; ++h) s += ad[h] * aerow[H1 + h];
            }
            if (l < LL - 1) {
                const float* ad = &adoc[l + 1][0];
                #pragma unroll
                for (int h = 0; h < H1; ++h) s += ad[h] * aerow[2 * H1 + h];
            }
            lg[l] = s;
        }
        __syncthreads();

        // softmax over L + weighted sum (wave 0; exact reduction)
        if (tid < 64) {
            const int lane = tid;
            float mx = -1e30f;
            for (int p = lane; p < LL; p += 64) mx = fmaxf(mx, lg[p]);
            #pragma unroll
            for (int o = 32; o; o >>= 1) mx = fmaxf(mx, __shfl_xor(mx, o, 64));
            float sum = 0.f;
            for (int p = lane; p < LL; p += 64) {
                float pr = expf(lg[p] - mx);
                lg[p] = pr;
                sum += pr;
            }
            #pragma unroll
            for (int o = 32; o; o >>= 1) sum += __shfl_xor(sum, o, 64);
            float r[H1];
            #pragma unroll
            for (int h = 0; h < H1; ++h) r[h] = 0.f;
            for (int p = lane; p < LL; p += 64) {
                const float pr = lg[p];
                const float* ad = &adoc[p][0];
                #pragma unroll
                for (int h = 0; h < H1; ++h) r[h] += pr * ad[h];
            }
            #pragma unroll
            for (int h = 0; h < H1; ++h) {
                #pragma unroll
                for (int o = 32; o; o >>= 1) r[h] += __shfl_xor(r[h], o, 64);
            }
            if (lane == 0) {
                const float inv = 1.f / sum;
                float* out = Rep + (((long)side * NB + b) * NA + a_) * H1;
                #pragma unroll
                for (int h = 0; h < H1; ++h) out[h] = r[h] * inv;
            }
        }
    }
}

__global__ __launch_bounds__(64)
void k_final(const float* __restrict__ Rep, const int* __restrict__ Uids,
             const int* __restrict__ Iids, const float* __restrict__ M,
             const float* __restrict__ Uproj, const float* __restrict__ Uw,
             const float* __restrict__ Iproj, const float* __restrict__ Iw,
             const float* __restrict__ Bu, const float* __restrict__ Bi,
             const float* __restrict__ Bg, float* __restrict__ out)
{
    __shared__ float Ud[50], Idd[50], tmp[50], aff[25];
    const int b = blockIdx.x, lane = threadIdx.x;
    if (lane < 50) {
        Ud[lane]  = Rep[(long)b * 50 + lane];
        Idd[lane] = Rep[(long)NB * 50 + (long)b * 50 + lane];
    }
    __syncthreads();
    if (lane < 50) {  // tmp[c][h] = sum_k M[h][k] * Id[c][k]
        const int c = lane / 10, h = lane % 10;
        float t = 0.f;
        #pragma unroll
        for (int k = 0; k < 10; ++k) t += M[h * 10 + k] * Idd[c * 10 + k];
        tmp[lane] = t;
    }
    __syncthreads();
    if (lane < 25) {  // aff[a][c] = relu(sum_h Ud[a][h] * tmp[c][h])
        const int a_ = lane / 5, c = lane % 5;
        float s = 0.f;
        #pragma unroll
        for (int h = 0; h < 10; ++h) s += Ud[a_ * 10 + h] * tmp[c * 10 + h];
        aff[lane] = fmaxf(s, 0.f);
    }
    __syncthreads();

    float hu1[5], hi1[5], tu[5], ti[5];
    if (lane < 50) {
        #pragma unroll
        for (int a_ = 0; a_ < 5; ++a_) {
            float su = 0.f, si = 0.f;
            #pragma unroll
            for (int h = 0; h < 10; ++h) {
                su += Uproj[lane * 10 + h] * Ud[a_ * 10 + h];
                si += Iproj[lane * 10 + h] * Idd[a_ * 10 + h];
            }
            hu1[a_] = su; hi1[a_] = si;
        }
    } else {
        #pragma unroll
        for (int a_ = 0; a_ < 5; ++a_) { hu1[a_] = 0.f; hi1[a_] = 0.f; }
    }
    const float uw = (lane < 50) ? Uw[lane] : 0.f;
    const float iw = (lane < 50) ? Iw[lane] : 0.f;
    #pragma unroll
    for (int a_ = 0; a_ < 5; ++a_) {
        float hu = hu1[a_], hi = hi1[a_];
        #pragma unroll
        for (int c = 0; c < 5; ++c) {
            hu += hi1[c] * aff[a_ * 5 + c];   // Hu[e][a] += Hi1[e][c]*aff[a][c]
            hi += hu1[c] * aff[c * 5 + a_];   // Hi[e][c] += Hu1[e][a]*aff[a][c]
        }
        tu[a_] = uw * fmaxf(hu, 0.f);
        ti[a_] = iw * fmaxf(hi, 0.f);
    }
    #pragma unroll
    for (int a_ = 0; a_ < 5; ++a_) {
        #pragma unroll
        for (int o = 32; o; o >>= 1) {
            tu[a_] += __shfl_xor(tu[a_], o, 64);
            ti[a_] += __shfl_xor(ti[a_], o, 64);
        }
    }
    if (lane == 0) {
        float mu = tu[0], mi = ti[0];
        #pragma unroll
        for (int a_ = 1; a_ < 5; ++a_) { mu = fmaxf(mu, tu[a_]); mi = fmaxf(mi, ti[a_]); }
        float eu[5], ei[5], su = 0.f, si = 0.f;
        #pragma unroll
        for (int a_ = 0; a_ < 5; ++a_) {
            eu[a_] = expf(tu[a_] - mu); su += eu[a_];
            ei[a_] = expf(ti[a_] - mi); si += ei[a_];
        }
        float R = 0.f;
        #pragma unroll
        for (int a_ = 0; a_ < 5; ++a_) {
            float ar = 0.f;
            #pragma unroll
            for (int h = 0; h < 10; ++h) ar += Ud[a_ * 10 + h] * Idd[a_ * 10 + h];
            R += (eu[a_] / su) * (ei[a_] / si) * ar;
        }
        R += Bu[Uids[b]] + Bi[Iids[b]] + Bg[0];
        out[b] = R;
    }
}

extern "C" void kernel_launch(void* const* d_in, const int* in_sizes, int n_in,
                              void* d_out, int out_size, void* d_ws, size_t ws_size,
                              hipStream_t stream)
{
    const int*   Uids  = (const int*)d_in[0];
    const int*   Iids  = (const int*)d_in[1];
    const int*   Udocs = (const int*)d_in[2];
    const int*   Idocs = (const int*)d_in[3];
    const float* Wemb  = (const float*)d_in[4];
    const float* AE    = (const float*)d_in[5];
    const float* AP    = (const float*)d_in[6];
    const float* M     = (const float*)d_in[7];
    const float* Uproj = (const float*)d_in[8];
    const float* Uw    = (const float*)d_in[9];
    const float* Iproj = (const float*)d_in[10];
    const float* Iw    = (const float*)d_in[11];
    const float* Bu    = (const float*)d_in[12];
    const float* Bi    = (const float*)d_in[13];
    const float* Bg    = (const float*)d_in[14];

    float* Rep = (float*)d_ws;        // [2][256][5][10] = 102400 B
    float* out = (float*)d_out;

    const size_t smem = 15200 + 22000 + 2000;   // apS + adoc + lg = 39200 B
    k_aspect<<<2 * NB, 256, smem, stream>>>(Uids, Iids, Udocs, Idocs, Wemb, AE, AP, Rep);
    k_final<<<NB, 64, 0, stream>>>(Rep, Uids, Iids, M, Uproj, Uw, Iproj, Iw, Bu, Bi, Bg, out);
}